// Round 7
// baseline (308.953 us; speedup 1.0000x reference)
//
#include <hip/hip_runtime.h>

#define CIN 8
#define COUT 32
#define NR 2
#define EPSF 1e-6f

#define BSH 6                   // log2 nodes per bucket
#define BNODES 64               // nodes per bucket
#define NBMAX 1024              // supports N <= 65536
#define CHUNK 8192              // edges per binify block
#define IDBITS 21               // supports E < 2^21
#define IDMASK ((1u << IDBITS) - 1u)
#define SRCMASK 0x03FFFFFFu     // low 26 bits of meta = src node
#define STAGE_MAX 4096          // per-bucket staging capacity (avg 2048)

// ---------------- pass 1: coarse bucket histogram ----------------
__global__ __launch_bounds__(256) void bucket_hist(
    const int* __restrict__ eidx, int* __restrict__ bucketCnt, int E, int nb)
{
    __shared__ int cnt[NBMAX];
    for (int i = threadIdx.x; i < nb; i += 256) cnt[i] = 0;
    __syncthreads();
    for (int e = blockIdx.x * 256 + threadIdx.x; e < E; e += gridDim.x * 256)
        atomicAdd(&cnt[eidx[E + e] >> BSH], 1);
    __syncthreads();
    for (int i = threadIdx.x; i < nb; i += 256)
        if (cnt[i]) atomicAdd(&bucketCnt[i], cnt[i]);
}

// ---------------- pass 2: single-block scan -> bucket bases ----------------
__global__ __launch_bounds__(1024) void scan_init(
    const int* __restrict__ bucketCnt, int* __restrict__ bucketBase,
    int* __restrict__ gCursor, int nb)
{
    __shared__ int sA[NBMAX], sB[NBMAX];
    const int t = threadIdx.x;
    sA[t] = (t < nb) ? bucketCnt[t] : 0;
    __syncthreads();
    int* src = sA; int* dst = sB;
    for (int off = 1; off < NBMAX; off <<= 1) {
        dst[t] = src[t] + (t >= off ? src[t - off] : 0);
        __syncthreads();
        int* tmp = src; src = dst; dst = tmp;
    }
    if (t < nb) {
        int incl = src[t];
        int base = incl - bucketCnt[t];
        bucketBase[t] = base;
        gCursor[t] = base;
        if (t == nb - 1) bucketBase[nb] = incl;
    }
}

// ------- pass 3: bin edges by bucket; PACKED also reorders pcmp+src --------
template<bool PACKED>
__global__ __launch_bounds__(256) void binify(
    const int* __restrict__ eidx, int* __restrict__ gCursor,
    unsigned* __restrict__ outMeta,     // PACKED: (dl<<26)|src ; else (dl<<21)|e
    float4*   __restrict__ pcmpS,       // PACKED only: reordered pcmp
    const float* __restrict__ pcmp, int E, int nb)
{
    __shared__ int cnt[NBMAX];
    __shared__ int sA[NBMAX], sB[NBMAX];
    __shared__ int gbase[NBMAX];
    __shared__ unsigned sid[CHUNK];

    const int e0 = blockIdx.x * CHUNK;
    const int num = min(CHUNK, E - e0);

    for (int i = threadIdx.x; i < nb; i += 256) cnt[i] = 0;
    __syncthreads();
    for (int k = threadIdx.x; k < num; k += 256)
        atomicAdd(&cnt[eidx[E + e0 + k] >> BSH], 1);
    __syncthreads();

    for (int j = threadIdx.x; j < NBMAX; j += 256) sA[j] = (j < nb) ? cnt[j] : 0;
    __syncthreads();
    int* src = sA; int* dstp = sB;
    for (int off = 1; off < NBMAX; off <<= 1) {
        for (int j = threadIdx.x; j < NBMAX; j += 256)
            dstp[j] = src[j] + (j >= off ? src[j - off] : 0);
        __syncthreads();
        int* tmp = src; src = dstp; dstp = tmp;
    }

    for (int b = threadIdx.x; b < nb; b += 256)
        gbase[b] = atomicAdd(&gCursor[b], cnt[b]);
    __syncthreads();
    for (int i = threadIdx.x; i < nb; i += 256) cnt[i] = 0;   // reuse as cursor
    __syncthreads();

    for (int k = threadIdx.x; k < num; k += 256) {
        int e = e0 + k;
        int d = eidx[E + e];
        int b = d >> BSH;
        int slot = (b ? src[b - 1] : 0) + atomicAdd(&cnt[b], 1);
        sid[slot] = ((unsigned)(d & (BNODES - 1)) << IDBITS) | (unsigned)e;
    }
    __syncthreads();

    // coalesced segment write-out
    for (int s = threadIdx.x; s < num; s += 256) {
        int lo = 0, hi = nb;
        while (lo < hi) { int mid = (lo + hi) >> 1; if (src[mid] > s) hi = mid; else lo = mid + 1; }
        int b = lo;
        int intra = s - (b ? src[b - 1] : 0);
        unsigned v = sid[s];
        int pos = gbase[b] + intra;
        if (PACKED) {
            int id = v & IDMASK;
            unsigned dl = v >> IDBITS;
            unsigned sv = (unsigned)eidx[id];
            outMeta[pos] = (dl << 26) | sv;
            pcmpS[pos] = *reinterpret_cast<const float4*>(pcmp + (size_t)id * 4);
        } else {
            outMeta[pos] = v;
        }
    }
}

// ---- pass 4: per-bucket LDS counting-sort + 4-way interleaved reg accum ----
__global__ __launch_bounds__(512) void fused_sorted_kernel(
    const float* __restrict__ x,          // [N, CIN]
    const float4* __restrict__ pcmpS,     // reordered pcmp, bucket-segmented
    const unsigned* __restrict__ meta,    // (dl<<26)|src per slot
    const int* __restrict__ bucketBase,   // [nb+1]
    const float* __restrict__ W_rad, const float* __restrict__ phase,
    const float* __restrict__ b_nl,
    const float* __restrict__ W1, const float* __restrict__ b1,
    const float* __restrict__ W2, const float* __restrict__ b2,
    const float* __restrict__ W3, const float* __restrict__ b3,
    float* __restrict__ out, int N)
{
    __shared__ float sWrad[NR * CIN][COUT];        // 2 KB
    __shared__ float sW[3][COUT][COUT];            // 12 KB
    __shared__ float sPh[COUT][2];
    __shared__ float sBias[4][COUT];
    __shared__ unsigned srtSrc[STAGE_MAX];         // 16 KB
    __shared__ unsigned short srtK[STAGE_MAX];     // 8 KB
    __shared__ int cnt[BNODES], segS[BNODES], cur[BNODES];

    for (int i = threadIdx.x; i < NR * CIN * COUT; i += 512) ((float*)sWrad)[i] = W_rad[i];
    for (int i = threadIdx.x; i < COUT * COUT; i += 512) {
        ((float*)sW[0])[i] = W1[i];
        ((float*)sW[1])[i] = W2[i];
        ((float*)sW[2])[i] = W3[i];
    }
    if (threadIdx.x < COUT) {
        float sn, cs; __sincosf(phase[threadIdx.x], &sn, &cs);
        sPh[threadIdx.x][0] = cs; sPh[threadIdx.x][1] = sn;
        sBias[0][threadIdx.x] = b_nl[threadIdx.x];
        sBias[1][threadIdx.x] = b1[threadIdx.x];
        sBias[2][threadIdx.x] = b2[threadIdx.x];
        sBias[3][threadIdx.x] = b3[threadIdx.x];
    }
    if (threadIdx.x < BNODES) cnt[threadIdx.x] = 0;
    __syncthreads();

    const int start  = bucketBase[blockIdx.x];
    const int total  = bucketBase[blockIdx.x + 1] - start;
    const int staged = min(total, STAGE_MAX);

    // ---- histogram by local node ----
    for (int k = threadIdx.x; k < staged; k += 512)
        atomicAdd(&cnt[meta[start + k] >> 26], 1);
    __syncthreads();

    // ---- exclusive scan over 64 counters (wave 0) ----
    if (threadIdx.x < 64) {
        int v = cnt[threadIdx.x];
        int incl = v;
#pragma unroll
        for (int off = 1; off < 64; off <<= 1) {
            int u = __shfl_up(incl, off, 64);
            if (threadIdx.x >= off) incl += u;
        }
        segS[threadIdx.x] = incl - v;
        cur[threadIdx.x]  = incl - v;
    }
    __syncthreads();

    // ---- scatter (src, k) into node-sorted LDS order ----
    for (int k = threadIdx.x; k < staged; k += 512) {
        unsigned m = meta[start + k];
        int dl = m >> 26;
        int pos = atomicAdd(&cur[dl], 1);
        srtSrc[pos] = m & SRCMASK;
        srtK[pos] = (unsigned short)k;
    }
    __syncthreads();

    const int c   = threadIdx.x & 31;     // channel / lane in half-wave
    const int sub = threadIdx.x >> 5;     // subgroup 0..15
    const int i_idx  = (c >> 1) & 7;
    const int pc_off = ((c >> 4) << 1) | (c & 1);
    const float* pcf = (const float*)(pcmpS + start);
    const int node0 = blockIdx.x << BSH;

    // ---- 4 node-slots per subgroup, interleaved (4 independent chains) ----
    int s0a[4], lena[4];
#pragma unroll
    for (int r = 0; r < 4; ++r) {
        int gl = sub * 4 + r;
        s0a[r]  = segS[gl];
        lena[r] = cnt[gl];
    }
    float q[4] = {0.f, 0.f, 0.f, 0.f};
    int maxl = max(max(lena[0], lena[1]), max(lena[2], lena[3]));
#pragma unroll 2
    for (int t = 0; t < maxl; ++t) {
#pragma unroll
        for (int r = 0; r < 4; ++r) {
            if (t < lena[r]) {
                int j = s0a[r] + t;
                unsigned sa = srtSrc[j];
                unsigned ka = srtK[j];
                q[r] += x[(size_t)sa * CIN + i_idx] * pcf[(size_t)ka * 4 + pc_off];
            }
        }
    }
    // overflow fallback (bucket > STAGE_MAX; never for this data)
    if (total > staged) {
#pragma unroll
        for (int r = 0; r < 4; ++r) {
            int gl = sub * 4 + r;
            for (int t2 = staged; t2 < total; ++t2) {
                unsigned m = meta[start + t2];
                if ((int)(m >> 26) == gl)
                    q[r] += x[(size_t)(m & SRCMASK) * CIN + i_idx]
                          * pcf[(size_t)t2 * 4 + pc_off];
            }
        }
    }

    // ---- epilogue per slot, straight from registers (half-wave shuffles) ----
#pragma unroll
    for (int r = 0; r < 4; ++r) {
        const int gl = sub * 4 + r;
        const int n  = node0 + gl;
        float a0 = 0.f, a1 = 0.f;
#pragma unroll
        for (int ri = 0; ri < NR * CIN; ++ri) {
            float w = sWrad[ri][c];
            a0 += w * __shfl(q[r], 2 * ri,     32);
            a1 += w * __shfl(q[r], 2 * ri + 1, 32);
        }
        float cs = sPh[c][0], sn = sPh[c][1];
        float re = a0 * cs - a1 * sn;
        float im = a0 * sn + a1 * cs;
        float mag = sqrtf(re * re + im * im + EPSF);
        float sc  = fmaxf(mag + sBias[0][c], 0.f) / mag;
        re *= sc; im *= sc;
#pragma unroll
        for (int L = 0; L < 3; ++L) {
            float b0 = 0.f, b1v = 0.f;
#pragma unroll
            for (int i = 0; i < COUT; ++i) {
                float w = sW[L][i][c];
                b0  += w * __shfl(re, i, 32);
                b1v += w * __shfl(im, i, 32);
            }
            float m2 = sqrtf(b0 * b0 + b1v * b1v + EPSF);
            float s2 = fmaxf(m2 + sBias[L + 1][c], 0.f) / m2;
            re = b0 * s2; im = b1v * s2;
        }
        if (n < N) {
            float2 v; v.x = re; v.y = im;
            *reinterpret_cast<float2*>(out + ((size_t)n * COUT + c) * 2) = v;
        }
    }
}

// ---------------- fallback fused kernel (meta-only, LDS atomics) ------------
__global__ __launch_bounds__(256) void fused_bucket_fallback(
    const float* __restrict__ x, const int* __restrict__ eidx,
    const float* __restrict__ pcmp, const int* __restrict__ bucketBase,
    const unsigned* __restrict__ sorted,
    const float* __restrict__ W_rad, const float* __restrict__ phase,
    const float* __restrict__ b_nl,
    const float* __restrict__ W1, const float* __restrict__ b1,
    const float* __restrict__ W2, const float* __restrict__ b2,
    const float* __restrict__ W3, const float* __restrict__ b3,
    float* __restrict__ out, int N)
{
    __shared__ float Q[BNODES][COUT];
    __shared__ float sWrad[NR * CIN][COUT];
    __shared__ float sW[3][COUT][COUT];
    __shared__ float sPh[COUT][2];
    __shared__ float sBias[4][COUT];

    for (int i = threadIdx.x; i < BNODES * COUT; i += 256) ((float*)Q)[i] = 0.f;
    for (int i = threadIdx.x; i < NR * CIN * COUT; i += 256) ((float*)sWrad)[i] = W_rad[i];
    for (int i = threadIdx.x; i < COUT * COUT; i += 256) {
        ((float*)sW[0])[i] = W1[i];
        ((float*)sW[1])[i] = W2[i];
        ((float*)sW[2])[i] = W3[i];
    }
    if (threadIdx.x < COUT) {
        float sn, cs; __sincosf(phase[threadIdx.x], &sn, &cs);
        sPh[threadIdx.x][0] = cs; sPh[threadIdx.x][1] = sn;
        sBias[0][threadIdx.x] = b_nl[threadIdx.x];
        sBias[1][threadIdx.x] = b1[threadIdx.x];
        sBias[2][threadIdx.x] = b2[threadIdx.x];
        sBias[3][threadIdx.x] = b3[threadIdx.x];
    }
    __syncthreads();

    const int c   = threadIdx.x & 31;
    const int sub = threadIdx.x >> 5;
    const int i_idx  = (c >> 1) & 7;
    const int pc_off = ((c >> 4) << 1) | (c & 1);
    const int start = bucketBase[blockIdx.x];
    const int end   = bucketBase[blockIdx.x + 1];

    for (int p = start + sub; p < end; p += 8) {
        unsigned v0 = sorted[p];
        int id0 = v0 & IDMASK;
        int s0 = eidx[id0];
        atomicAdd(&Q[v0 >> IDBITS][c],
                  x[(size_t)s0 * CIN + i_idx] * pcmp[(size_t)id0 * 4 + pc_off]);
    }
    __syncthreads();

    const int node0 = blockIdx.x << BSH;
#pragma unroll
    for (int r = 0; r < 8; ++r) {
        const int gl = r * 8 + sub;
        const int n  = node0 + gl;
        float a0 = 0.f, a1 = 0.f;
#pragma unroll
        for (int ri = 0; ri < NR * CIN; ++ri) {
            float w = sWrad[ri][c];
            a0 += w * Q[gl][2 * ri];
            a1 += w * Q[gl][2 * ri + 1];
        }
        float cs = sPh[c][0], sn = sPh[c][1];
        float re = a0 * cs - a1 * sn;
        float im = a0 * sn + a1 * cs;
        float mag = sqrtf(re * re + im * im + EPSF);
        float sc  = fmaxf(mag + sBias[0][c], 0.f) / mag;
        re *= sc; im *= sc;
#pragma unroll
        for (int L = 0; L < 3; ++L) {
            float b0 = 0.f, b1v = 0.f;
#pragma unroll
            for (int i = 0; i < COUT; ++i) {
                float w = sW[L][i][c];
                b0  += w * __shfl(re, i, 32);
                b1v += w * __shfl(im, i, 32);
            }
            float m2 = sqrtf(b0 * b0 + b1v * b1v + EPSF);
            float s2 = fmaxf(m2 + sBias[L + 1][c], 0.f) / m2;
            re = b0 * s2; im = b1v * s2;
        }
        if (n < N) {
            float2 v; v.x = re; v.y = im;
            *reinterpret_cast<float2*>(out + ((size_t)n * COUT + c) * 2) = v;
        }
    }
}

extern "C" void kernel_launch(void* const* d_in, const int* in_sizes, int n_in,
                              void* d_out, int out_size, void* d_ws, size_t ws_size,
                              hipStream_t stream)
{
    const float* x     = (const float*)d_in[0];
    const int*   eidx  = (const int*)  d_in[1];
    const float* pcmp  = (const float*)d_in[2];
    const float* W_rad = (const float*)d_in[3];
    const float* phase = (const float*)d_in[4];
    const float* b_nl  = (const float*)d_in[5];
    const float* W1    = (const float*)d_in[6];
    const float* b1    = (const float*)d_in[7];
    const float* W2    = (const float*)d_in[8];
    const float* b2    = (const float*)d_in[9];
    const float* W3    = (const float*)d_in[10];
    const float* b3    = (const float*)d_in[11];
    float* out = (float*)d_out;

    const int N = in_sizes[0] / CIN;
    const int E = in_sizes[1] / 2;
    const int nb = (N + BNODES - 1) >> BSH;
    const int nchunk = (E + CHUNK - 1) / CHUNK;

    // PACKED layout: pcmpS[E] (16B) | meta[E] (4B) | bucketCnt | bucketBase | gCursor
    float4*   pcmpS      = (float4*)d_ws;
    unsigned* meta       = (unsigned*)(pcmpS + E);
    int*      bucketCnt  = (int*)(meta + E);
    int*      bucketBase = bucketCnt + NBMAX;
    int*      gCursor    = bucketBase + NBMAX + 1;
    size_t needed = (size_t)((char*)(gCursor + NBMAX) - (char*)d_ws);

    if (ws_size >= needed) {
        hipMemsetAsync(bucketCnt, 0, (size_t)nb * sizeof(int), stream);
        bucket_hist<<<256, 256, 0, stream>>>(eidx, bucketCnt, E, nb);
        scan_init<<<1, 1024, 0, stream>>>(bucketCnt, bucketBase, gCursor, nb);
        binify<true><<<nchunk, 256, 0, stream>>>(eidx, gCursor, meta, pcmpS, pcmp, E, nb);
        fused_sorted_kernel<<<nb, 512, 0, stream>>>(
            x, pcmpS, meta, bucketBase,
            W_rad, phase, b_nl, W1, b1, W2, b2, W3, b3, out, N);
    } else {
        int*      bc = (int*)d_ws;
        int*      bb = bc + NBMAX;
        int*      gc = bb + NBMAX + 1;
        unsigned* so = (unsigned*)(gc + NBMAX);
        hipMemsetAsync(bc, 0, (size_t)nb * sizeof(int), stream);
        bucket_hist<<<256, 256, 0, stream>>>(eidx, bc, E, nb);
        scan_init<<<1, 1024, 0, stream>>>(bc, bb, gc, nb);
        binify<false><<<nchunk, 256, 0, stream>>>(eidx, gc, so, nullptr, pcmp, E, nb);
        fused_bucket_fallback<<<nb, 256, 0, stream>>>(
            x, eidx, pcmp, bb, so,
            W_rad, phase, b_nl, W1, b1, W2, b2, W3, b3, out, N);
    }
}

// Round 8
// 215.315 us; speedup vs baseline: 1.4349x; 1.4349x over previous
//
#include <hip/hip_runtime.h>

#define CIN 8
#define COUT 32
#define NR 2
#define EPSF 1e-6f

#define BSH 6                   // log2 nodes per bucket
#define BNODES 64               // nodes per bucket
#define NBMAX 1024              // supports N <= 65536
#define CHUNK 8192              // edges per binify block
#define IDBITS 21               // supports E < 2^21
#define IDMASK ((1u << IDBITS) - 1u)
#define SRCMASK 0x03FFFFFFu     // low 26 bits of meta = src node
#define STAGE_MAX 4096          // per-bucket staging capacity (avg 2048)

// ---------------- pass 1: coarse bucket histogram ----------------
__global__ __launch_bounds__(256) void bucket_hist(
    const int* __restrict__ eidx, int* __restrict__ bucketCnt, int E, int nb)
{
    __shared__ int cnt[NBMAX];
    for (int i = threadIdx.x; i < nb; i += 256) cnt[i] = 0;
    __syncthreads();
    for (int e = blockIdx.x * 256 + threadIdx.x; e < E; e += gridDim.x * 256)
        atomicAdd(&cnt[eidx[E + e] >> BSH], 1);
    __syncthreads();
    for (int i = threadIdx.x; i < nb; i += 256)
        if (cnt[i]) atomicAdd(&bucketCnt[i], cnt[i]);
}

// ---------------- pass 2: single-block scan -> bucket bases ----------------
__global__ __launch_bounds__(1024) void scan_init(
    const int* __restrict__ bucketCnt, int* __restrict__ bucketBase,
    int* __restrict__ gCursor, int nb)
{
    __shared__ int sA[NBMAX], sB[NBMAX];
    const int t = threadIdx.x;
    sA[t] = (t < nb) ? bucketCnt[t] : 0;
    __syncthreads();
    int* src = sA; int* dst = sB;
    for (int off = 1; off < NBMAX; off <<= 1) {
        dst[t] = src[t] + (t >= off ? src[t - off] : 0);
        __syncthreads();
        int* tmp = src; src = dst; dst = tmp;
    }
    if (t < nb) {
        int incl = src[t];
        int base = incl - bucketCnt[t];
        bucketBase[t] = base;
        gCursor[t] = base;
        if (t == nb - 1) bucketBase[nb] = incl;
    }
}

// ------- pass 3: bin edges by bucket; PACKED also reorders pcmp+src --------
template<bool PACKED>
__global__ __launch_bounds__(256) void binify(
    const int* __restrict__ eidx, int* __restrict__ gCursor,
    unsigned* __restrict__ outMeta,     // PACKED: (dl<<26)|src ; else (dl<<21)|e
    float4*   __restrict__ pcmpS,       // PACKED only: reordered pcmp
    const float* __restrict__ pcmp, int E, int nb)
{
    __shared__ int cnt[NBMAX];
    __shared__ int sA[NBMAX], sB[NBMAX];
    __shared__ int gbase[NBMAX];
    __shared__ unsigned sid[CHUNK];

    const int e0 = blockIdx.x * CHUNK;
    const int num = min(CHUNK, E - e0);

    for (int i = threadIdx.x; i < nb; i += 256) cnt[i] = 0;
    __syncthreads();
    for (int k = threadIdx.x; k < num; k += 256)
        atomicAdd(&cnt[eidx[E + e0 + k] >> BSH], 1);
    __syncthreads();

    for (int j = threadIdx.x; j < NBMAX; j += 256) sA[j] = (j < nb) ? cnt[j] : 0;
    __syncthreads();
    int* src = sA; int* dstp = sB;
    for (int off = 1; off < NBMAX; off <<= 1) {
        for (int j = threadIdx.x; j < NBMAX; j += 256)
            dstp[j] = src[j] + (j >= off ? src[j - off] : 0);
        __syncthreads();
        int* tmp = src; src = dstp; dstp = tmp;
    }

    for (int b = threadIdx.x; b < nb; b += 256)
        gbase[b] = atomicAdd(&gCursor[b], cnt[b]);
    __syncthreads();
    for (int i = threadIdx.x; i < nb; i += 256) cnt[i] = 0;   // reuse as cursor
    __syncthreads();

    for (int k = threadIdx.x; k < num; k += 256) {
        int e = e0 + k;
        int d = eidx[E + e];
        int b = d >> BSH;
        int slot = (b ? src[b - 1] : 0) + atomicAdd(&cnt[b], 1);
        sid[slot] = ((unsigned)(d & (BNODES - 1)) << IDBITS) | (unsigned)e;
    }
    __syncthreads();

    // coalesced segment write-out
    for (int s = threadIdx.x; s < num; s += 256) {
        int lo = 0, hi = nb;
        while (lo < hi) { int mid = (lo + hi) >> 1; if (src[mid] > s) hi = mid; else lo = mid + 1; }
        int b = lo;
        int intra = s - (b ? src[b - 1] : 0);
        unsigned v = sid[s];
        int pos = gbase[b] + intra;
        if (PACKED) {
            int id = v & IDMASK;
            unsigned dl = v >> IDBITS;
            unsigned sv = (unsigned)eidx[id];
            outMeta[pos] = (dl << 26) | sv;
            pcmpS[pos] = *reinterpret_cast<const float4*>(pcmp + (size_t)id * 4);
        } else {
            outMeta[pos] = v;
        }
    }
}

// ---- pass 4: per-bucket LDS counting-sort + 4x-unrolled reg accumulation ---
// P16: pack (k<<16)|src into one LDS word (requires N <= 65536)
template<bool P16>
__global__ __launch_bounds__(256) void fused_sorted_kernel(
    const float* __restrict__ x,          // [N, CIN]
    const float4* __restrict__ pcmpS,     // reordered pcmp, bucket-segmented
    const unsigned* __restrict__ meta,    // (dl<<26)|src per slot
    const int* __restrict__ bucketBase,   // [nb+1]
    const float* __restrict__ W_rad, const float* __restrict__ phase,
    const float* __restrict__ b_nl,
    const float* __restrict__ W1, const float* __restrict__ b1,
    const float* __restrict__ W2, const float* __restrict__ b2,
    const float* __restrict__ W3, const float* __restrict__ b3,
    float* __restrict__ out, int N)
{
    __shared__ float sWrad[NR * CIN][COUT];        // 2 KB
    __shared__ float sW[3][COUT][COUT];            // 12 KB
    __shared__ float sPh[COUT][2];
    __shared__ float sBias[4][COUT];
    __shared__ unsigned srtPk[STAGE_MAX];          // 16 KB: P16 ? (k<<16|src) : src
    __shared__ unsigned short srtK[STAGE_MAX];     // 8 KB, only referenced if !P16
    __shared__ int cnt[BNODES], segS[BNODES], cur[BNODES];

    for (int i = threadIdx.x; i < NR * CIN * COUT; i += 256) ((float*)sWrad)[i] = W_rad[i];
    for (int i = threadIdx.x; i < COUT * COUT; i += 256) {
        ((float*)sW[0])[i] = W1[i];
        ((float*)sW[1])[i] = W2[i];
        ((float*)sW[2])[i] = W3[i];
    }
    if (threadIdx.x < COUT) {
        float sn, cs; __sincosf(phase[threadIdx.x], &sn, &cs);
        sPh[threadIdx.x][0] = cs; sPh[threadIdx.x][1] = sn;
        sBias[0][threadIdx.x] = b_nl[threadIdx.x];
        sBias[1][threadIdx.x] = b1[threadIdx.x];
        sBias[2][threadIdx.x] = b2[threadIdx.x];
        sBias[3][threadIdx.x] = b3[threadIdx.x];
    }
    if (threadIdx.x < BNODES) cnt[threadIdx.x] = 0;
    __syncthreads();

    const int start  = bucketBase[blockIdx.x];
    const int total  = bucketBase[blockIdx.x + 1] - start;
    const int staged = min(total, STAGE_MAX);

    // ---- histogram by local node ----
    for (int k = threadIdx.x; k < staged; k += 256)
        atomicAdd(&cnt[meta[start + k] >> 26], 1);
    __syncthreads();

    // ---- exclusive scan over 64 counters (wave 0) ----
    if (threadIdx.x < 64) {
        int v = cnt[threadIdx.x];
        int incl = v;
#pragma unroll
        for (int off = 1; off < 64; off <<= 1) {
            int u = __shfl_up(incl, off, 64);
            if (threadIdx.x >= off) incl += u;
        }
        segS[threadIdx.x] = incl - v;
        cur[threadIdx.x]  = incl - v;
    }
    __syncthreads();

    // ---- scatter (src, k) into node-sorted LDS order ----
    for (int k = threadIdx.x; k < staged; k += 256) {
        unsigned m = meta[start + k];
        int dl = m >> 26;
        int pos = atomicAdd(&cur[dl], 1);
        if (P16) {
            srtPk[pos] = ((unsigned)k << 16) | (m & 0xFFFFu);
        } else {
            srtPk[pos] = m & SRCMASK;
            srtK[pos] = (unsigned short)k;
        }
    }
    __syncthreads();

    const int c   = threadIdx.x & 31;     // channel / lane in half-wave
    const int sub = threadIdx.x >> 5;     // subgroup 0..7
    const int i_idx  = (c >> 1) & 7;
    const int pc_off = ((c >> 4) << 1) | (c & 1);
    const float* pcf = (const float*)(pcmpS + start);
    const int node0 = blockIdx.x << BSH;

#pragma unroll
    for (int r = 0; r < 8; ++r) {
        const int gl = r * 8 + sub;
        const int n  = node0 + gl;
        const int s0 = segS[gl];
        const int e0 = s0 + cnt[gl];

        // ---- 4x straight-line unrolled register accumulation ----
        float q = 0.f;
        int j = s0;
        for (; j + 4 <= e0; j += 4) {
            unsigned p0, p1, p2, p3;
            unsigned k0, k1, k2, k3, s0v, s1v, s2v, s3v;
            if (P16) {
                p0 = srtPk[j];     p1 = srtPk[j + 1];
                p2 = srtPk[j + 2]; p3 = srtPk[j + 3];
                s0v = p0 & 0xFFFFu; k0 = p0 >> 16;
                s1v = p1 & 0xFFFFu; k1 = p1 >> 16;
                s2v = p2 & 0xFFFFu; k2 = p2 >> 16;
                s3v = p3 & 0xFFFFu; k3 = p3 >> 16;
            } else {
                s0v = srtPk[j];     k0 = srtK[j];
                s1v = srtPk[j + 1]; k1 = srtK[j + 1];
                s2v = srtPk[j + 2]; k2 = srtK[j + 2];
                s3v = srtPk[j + 3]; k3 = srtK[j + 3];
            }
            float x0 = x[(size_t)s0v * CIN + i_idx];
            float x1 = x[(size_t)s1v * CIN + i_idx];
            float x2 = x[(size_t)s2v * CIN + i_idx];
            float x3 = x[(size_t)s3v * CIN + i_idx];
            float c0 = pcf[(size_t)k0 * 4 + pc_off];
            float c1 = pcf[(size_t)k1 * 4 + pc_off];
            float c2 = pcf[(size_t)k2 * 4 + pc_off];
            float c3 = pcf[(size_t)k3 * 4 + pc_off];
            q += x0 * c0;
            q += x1 * c1;
            q += x2 * c2;
            q += x3 * c3;
        }
        for (; j < e0; ++j) {
            unsigned sv, kv;
            if (P16) {
                unsigned p = srtPk[j];
                sv = p & 0xFFFFu; kv = p >> 16;
            } else {
                sv = srtPk[j]; kv = srtK[j];
            }
            q += x[(size_t)sv * CIN + i_idx] * pcf[(size_t)kv * 4 + pc_off];
        }
        // overflow fallback (bucket > STAGE_MAX; never for this data)
        for (int t = staged; t < total; ++t) {
            unsigned m = meta[start + t];
            if ((int)(m >> 26) == gl)
                q += x[(size_t)(m & SRCMASK) * CIN + i_idx] * pcf[(size_t)t * 4 + pc_off];
        }

        // ---- epilogue straight from registers (half-wave shuffles) ----
        float a0 = 0.f, a1 = 0.f;
#pragma unroll
        for (int ri = 0; ri < NR * CIN; ++ri) {
            float w = sWrad[ri][c];
            a0 += w * __shfl(q, 2 * ri,     32);
            a1 += w * __shfl(q, 2 * ri + 1, 32);
        }
        float cs = sPh[c][0], sn = sPh[c][1];
        float re = a0 * cs - a1 * sn;
        float im = a0 * sn + a1 * cs;
        float mag = sqrtf(re * re + im * im + EPSF);
        float sc  = fmaxf(mag + sBias[0][c], 0.f) / mag;
        re *= sc; im *= sc;
#pragma unroll
        for (int L = 0; L < 3; ++L) {
            float b0 = 0.f, b1v = 0.f;
#pragma unroll
            for (int i = 0; i < COUT; ++i) {
                float w = sW[L][i][c];
                b0  += w * __shfl(re, i, 32);
                b1v += w * __shfl(im, i, 32);
            }
            float m2 = sqrtf(b0 * b0 + b1v * b1v + EPSF);
            float s2 = fmaxf(m2 + sBias[L + 1][c], 0.f) / m2;
            re = b0 * s2; im = b1v * s2;
        }
        if (n < N) {
            float2 v; v.x = re; v.y = im;
            *reinterpret_cast<float2*>(out + ((size_t)n * COUT + c) * 2) = v;
        }
    }
}

// ---------------- fallback fused kernel (meta-only, LDS atomics) ------------
__global__ __launch_bounds__(256) void fused_bucket_fallback(
    const float* __restrict__ x, const int* __restrict__ eidx,
    const float* __restrict__ pcmp, const int* __restrict__ bucketBase,
    const unsigned* __restrict__ sorted,
    const float* __restrict__ W_rad, const float* __restrict__ phase,
    const float* __restrict__ b_nl,
    const float* __restrict__ W1, const float* __restrict__ b1,
    const float* __restrict__ W2, const float* __restrict__ b2,
    const float* __restrict__ W3, const float* __restrict__ b3,
    float* __restrict__ out, int N)
{
    __shared__ float Q[BNODES][COUT];
    __shared__ float sWrad[NR * CIN][COUT];
    __shared__ float sW[3][COUT][COUT];
    __shared__ float sPh[COUT][2];
    __shared__ float sBias[4][COUT];

    for (int i = threadIdx.x; i < BNODES * COUT; i += 256) ((float*)Q)[i] = 0.f;
    for (int i = threadIdx.x; i < NR * CIN * COUT; i += 256) ((float*)sWrad)[i] = W_rad[i];
    for (int i = threadIdx.x; i < COUT * COUT; i += 256) {
        ((float*)sW[0])[i] = W1[i];
        ((float*)sW[1])[i] = W2[i];
        ((float*)sW[2])[i] = W3[i];
    }
    if (threadIdx.x < COUT) {
        float sn, cs; __sincosf(phase[threadIdx.x], &sn, &cs);
        sPh[threadIdx.x][0] = cs; sPh[threadIdx.x][1] = sn;
        sBias[0][threadIdx.x] = b_nl[threadIdx.x];
        sBias[1][threadIdx.x] = b1[threadIdx.x];
        sBias[2][threadIdx.x] = b2[threadIdx.x];
        sBias[3][threadIdx.x] = b3[threadIdx.x];
    }
    __syncthreads();

    const int c   = threadIdx.x & 31;
    const int sub = threadIdx.x >> 5;
    const int i_idx  = (c >> 1) & 7;
    const int pc_off = ((c >> 4) << 1) | (c & 1);
    const int start = bucketBase[blockIdx.x];
    const int end   = bucketBase[blockIdx.x + 1];

    for (int p = start + sub; p < end; p += 8) {
        unsigned v0 = sorted[p];
        int id0 = v0 & IDMASK;
        int s0 = eidx[id0];
        atomicAdd(&Q[v0 >> IDBITS][c],
                  x[(size_t)s0 * CIN + i_idx] * pcmp[(size_t)id0 * 4 + pc_off]);
    }
    __syncthreads();

    const int node0 = blockIdx.x << BSH;
#pragma unroll
    for (int r = 0; r < 8; ++r) {
        const int gl = r * 8 + sub;
        const int n  = node0 + gl;
        float a0 = 0.f, a1 = 0.f;
#pragma unroll
        for (int ri = 0; ri < NR * CIN; ++ri) {
            float w = sWrad[ri][c];
            a0 += w * Q[gl][2 * ri];
            a1 += w * Q[gl][2 * ri + 1];
        }
        float cs = sPh[c][0], sn = sPh[c][1];
        float re = a0 * cs - a1 * sn;
        float im = a0 * sn + a1 * cs;
        float mag = sqrtf(re * re + im * im + EPSF);
        float sc  = fmaxf(mag + sBias[0][c], 0.f) / mag;
        re *= sc; im *= sc;
#pragma unroll
        for (int L = 0; L < 3; ++L) {
            float b0 = 0.f, b1v = 0.f;
#pragma unroll
            for (int i = 0; i < COUT; ++i) {
                float w = sW[L][i][c];
                b0  += w * __shfl(re, i, 32);
                b1v += w * __shfl(im, i, 32);
            }
            float m2 = sqrtf(b0 * b0 + b1v * b1v + EPSF);
            float s2 = fmaxf(m2 + sBias[L + 1][c], 0.f) / m2;
            re = b0 * s2; im = b1v * s2;
        }
        if (n < N) {
            float2 v; v.x = re; v.y = im;
            *reinterpret_cast<float2*>(out + ((size_t)n * COUT + c) * 2) = v;
        }
    }
}

extern "C" void kernel_launch(void* const* d_in, const int* in_sizes, int n_in,
                              void* d_out, int out_size, void* d_ws, size_t ws_size,
                              hipStream_t stream)
{
    const float* x     = (const float*)d_in[0];
    const int*   eidx  = (const int*)  d_in[1];
    const float* pcmp  = (const float*)d_in[2];
    const float* W_rad = (const float*)d_in[3];
    const float* phase = (const float*)d_in[4];
    const float* b_nl  = (const float*)d_in[5];
    const float* W1    = (const float*)d_in[6];
    const float* b1    = (const float*)d_in[7];
    const float* W2    = (const float*)d_in[8];
    const float* b2    = (const float*)d_in[9];
    const float* W3    = (const float*)d_in[10];
    const float* b3    = (const float*)d_in[11];
    float* out = (float*)d_out;

    const int N = in_sizes[0] / CIN;
    const int E = in_sizes[1] / 2;
    const int nb = (N + BNODES - 1) >> BSH;
    const int nchunk = (E + CHUNK - 1) / CHUNK;

    // PACKED layout: pcmpS[E] (16B) | meta[E] (4B) | bucketCnt | bucketBase | gCursor
    float4*   pcmpS      = (float4*)d_ws;
    unsigned* meta       = (unsigned*)(pcmpS + E);
    int*      bucketCnt  = (int*)(meta + E);
    int*      bucketBase = bucketCnt + NBMAX;
    int*      gCursor    = bucketBase + NBMAX + 1;
    size_t needed = (size_t)((char*)(gCursor + NBMAX) - (char*)d_ws);

    if (ws_size >= needed) {
        hipMemsetAsync(bucketCnt, 0, (size_t)nb * sizeof(int), stream);
        bucket_hist<<<256, 256, 0, stream>>>(eidx, bucketCnt, E, nb);
        scan_init<<<1, 1024, 0, stream>>>(bucketCnt, bucketBase, gCursor, nb);
        binify<true><<<nchunk, 256, 0, stream>>>(eidx, gCursor, meta, pcmpS, pcmp, E, nb);
        if (N <= 65536) {
            fused_sorted_kernel<true><<<nb, 256, 0, stream>>>(
                x, pcmpS, meta, bucketBase,
                W_rad, phase, b_nl, W1, b1, W2, b2, W3, b3, out, N);
        } else {
            fused_sorted_kernel<false><<<nb, 256, 0, stream>>>(
                x, pcmpS, meta, bucketBase,
                W_rad, phase, b_nl, W1, b1, W2, b2, W3, b3, out, N);
        }
    } else {
        int*      bc = (int*)d_ws;
        int*      bb = bc + NBMAX;
        int*      gc = bb + NBMAX + 1;
        unsigned* so = (unsigned*)(gc + NBMAX);
        hipMemsetAsync(bc, 0, (size_t)nb * sizeof(int), stream);
        bucket_hist<<<256, 256, 0, stream>>>(eidx, bc, E, nb);
        scan_init<<<1, 1024, 0, stream>>>(bc, bb, gc, nb);
        binify<false><<<nchunk, 256, 0, stream>>>(eidx, gc, so, nullptr, pcmp, E, nb);
        fused_bucket_fallback<<<nb, 256, 0, stream>>>(
            x, eidx, pcmp, bb, so,
            W_rad, phase, b_nl, W1, b1, W2, b2, W3, b3, out, N);
    }
}

// Round 9
// 207.081 us; speedup vs baseline: 1.4919x; 1.0398x over previous
//
#include <hip/hip_runtime.h>

#define CIN 8
#define COUT 32
#define NR 2
#define EPSF 1e-6f

#define BSH 6                   // log2 nodes per bucket
#define BNODES 64               // nodes per bucket
#define NBMAX 1024              // supports N <= 65536
#define CHUNK 4096              // edges per binify block
#define IDBITS 21               // supports E < 2^21
#define IDMASK ((1u << IDBITS) - 1u)
#define SRCMASK 0x03FFFFFFu     // low 26 bits of meta = src node
#define STAGE_MAX 4096          // per-bucket staging capacity (avg 2048)
#define FTHREADS 512            // fused kernel block size
#define NSUB 16                 // subgroups in fused kernel
#define NPS 4                   // nodes per subgroup (NSUB*NPS = BNODES)

// ---------------- pass 1: coarse bucket histogram ----------------
__global__ __launch_bounds__(256) void bucket_hist(
    const int* __restrict__ eidx, int* __restrict__ bucketCnt, int E, int nb)
{
    __shared__ int cnt[NBMAX];
    for (int i = threadIdx.x; i < nb; i += 256) cnt[i] = 0;
    __syncthreads();
    for (int e = blockIdx.x * 256 + threadIdx.x; e < E; e += gridDim.x * 256)
        atomicAdd(&cnt[eidx[E + e] >> BSH], 1);
    __syncthreads();
    for (int i = threadIdx.x; i < nb; i += 256)
        if (cnt[i]) atomicAdd(&bucketCnt[i], cnt[i]);
}

// ---------------- pass 2: single-block scan -> bucket bases ----------------
__global__ __launch_bounds__(1024) void scan_init(
    const int* __restrict__ bucketCnt, int* __restrict__ bucketBase,
    int* __restrict__ gCursor, int nb)
{
    __shared__ int sA[NBMAX], sB[NBMAX];
    const int t = threadIdx.x;
    sA[t] = (t < nb) ? bucketCnt[t] : 0;
    __syncthreads();
    int* src = sA; int* dst = sB;
    for (int off = 1; off < NBMAX; off <<= 1) {
        dst[t] = src[t] + (t >= off ? src[t - off] : 0);
        __syncthreads();
        int* tmp = src; src = dst; dst = tmp;
    }
    if (t < nb) {
        int incl = src[t];
        int base = incl - bucketCnt[t];
        bucketBase[t] = base;
        gCursor[t] = base;
        if (t == nb - 1) bucketBase[nb] = incl;
    }
}

// ------- pass 3: bin edges by bucket; PACKED also reorders pcmp+src --------
template<bool PACKED>
__global__ __launch_bounds__(256) void binify(
    const int* __restrict__ eidx, int* __restrict__ gCursor,
    unsigned* __restrict__ outMeta,     // PACKED: (dl<<26)|src ; else (dl<<21)|e
    float4*   __restrict__ pcmpS,       // PACKED only: reordered pcmp
    const float* __restrict__ pcmp, int E, int nb)
{
    __shared__ int cnt[NBMAX];
    __shared__ int sA[NBMAX], sB[NBMAX];
    __shared__ int gbase[NBMAX];
    __shared__ unsigned sid[CHUNK];

    const int e0 = blockIdx.x * CHUNK;
    const int num = min(CHUNK, E - e0);

    for (int i = threadIdx.x; i < nb; i += 256) cnt[i] = 0;
    __syncthreads();
    for (int k = threadIdx.x; k < num; k += 256)
        atomicAdd(&cnt[eidx[E + e0 + k] >> BSH], 1);
    __syncthreads();

    for (int j = threadIdx.x; j < NBMAX; j += 256) sA[j] = (j < nb) ? cnt[j] : 0;
    __syncthreads();
    int* src = sA; int* dstp = sB;
    for (int off = 1; off < NBMAX; off <<= 1) {
        for (int j = threadIdx.x; j < NBMAX; j += 256)
            dstp[j] = src[j] + (j >= off ? src[j - off] : 0);
        __syncthreads();
        int* tmp = src; src = dstp; dstp = tmp;
    }

    for (int b = threadIdx.x; b < nb; b += 256)
        gbase[b] = atomicAdd(&gCursor[b], cnt[b]);
    __syncthreads();
    for (int i = threadIdx.x; i < nb; i += 256) cnt[i] = 0;   // reuse as cursor
    __syncthreads();

    for (int k = threadIdx.x; k < num; k += 256) {
        int e = e0 + k;
        int d = eidx[E + e];
        int b = d >> BSH;
        int slot = (b ? src[b - 1] : 0) + atomicAdd(&cnt[b], 1);
        sid[slot] = ((unsigned)(d & (BNODES - 1)) << IDBITS) | (unsigned)e;
    }
    __syncthreads();

    // coalesced segment write-out
    for (int s = threadIdx.x; s < num; s += 256) {
        int lo = 0, hi = nb;
        while (lo < hi) { int mid = (lo + hi) >> 1; if (src[mid] > s) hi = mid; else lo = mid + 1; }
        int b = lo;
        int intra = s - (b ? src[b - 1] : 0);
        unsigned v = sid[s];
        int pos = gbase[b] + intra;
        if (PACKED) {
            int id = v & IDMASK;
            unsigned dl = v >> IDBITS;
            unsigned sv = (unsigned)eidx[id];
            outMeta[pos] = (dl << 26) | sv;
            pcmpS[pos] = *reinterpret_cast<const float4*>(pcmp + (size_t)id * 4);
        } else {
            outMeta[pos] = v;
        }
    }
}

// ---- pass 4: per-bucket LDS counting-sort + 4x-unrolled reg accumulation ---
// 512 threads: 16 subgroups x 4 serial nodes. P16: pack (k<<16)|src (N<=65536).
template<bool P16>
__global__ __launch_bounds__(FTHREADS) void fused_sorted_kernel(
    const float* __restrict__ x,          // [N, CIN]
    const float4* __restrict__ pcmpS,     // reordered pcmp, bucket-segmented
    const unsigned* __restrict__ meta,    // (dl<<26)|src per slot
    const int* __restrict__ bucketBase,   // [nb+1]
    const float* __restrict__ W_rad, const float* __restrict__ phase,
    const float* __restrict__ b_nl,
    const float* __restrict__ W1, const float* __restrict__ b1,
    const float* __restrict__ W2, const float* __restrict__ b2,
    const float* __restrict__ W3, const float* __restrict__ b3,
    float* __restrict__ out, int N)
{
    __shared__ float sWrad[NR * CIN][COUT];        // 2 KB
    __shared__ float sW[3][COUT][COUT];            // 12 KB
    __shared__ float sPh[COUT][2];
    __shared__ float sBias[4][COUT];
    __shared__ unsigned srtPk[STAGE_MAX];          // 16 KB: P16 ? (k<<16|src) : src
    __shared__ unsigned short srtK[STAGE_MAX];     // 8 KB, only referenced if !P16
    __shared__ int cnt[BNODES], segS[BNODES], cur[BNODES];

    for (int i = threadIdx.x; i < NR * CIN * COUT; i += FTHREADS) ((float*)sWrad)[i] = W_rad[i];
    for (int i = threadIdx.x; i < COUT * COUT; i += FTHREADS) {
        ((float*)sW[0])[i] = W1[i];
        ((float*)sW[1])[i] = W2[i];
        ((float*)sW[2])[i] = W3[i];
    }
    if (threadIdx.x < COUT) {
        float sn, cs; __sincosf(phase[threadIdx.x], &sn, &cs);
        sPh[threadIdx.x][0] = cs; sPh[threadIdx.x][1] = sn;
        sBias[0][threadIdx.x] = b_nl[threadIdx.x];
        sBias[1][threadIdx.x] = b1[threadIdx.x];
        sBias[2][threadIdx.x] = b2[threadIdx.x];
        sBias[3][threadIdx.x] = b3[threadIdx.x];
    }
    if (threadIdx.x < BNODES) cnt[threadIdx.x] = 0;
    __syncthreads();

    const int start  = bucketBase[blockIdx.x];
    const int total  = bucketBase[blockIdx.x + 1] - start;
    const int staged = min(total, STAGE_MAX);

    // ---- histogram by local node ----
    for (int k = threadIdx.x; k < staged; k += FTHREADS)
        atomicAdd(&cnt[meta[start + k] >> 26], 1);
    __syncthreads();

    // ---- exclusive scan over 64 counters (wave 0) ----
    if (threadIdx.x < 64) {
        int v = cnt[threadIdx.x];
        int incl = v;
#pragma unroll
        for (int off = 1; off < 64; off <<= 1) {
            int u = __shfl_up(incl, off, 64);
            if (threadIdx.x >= off) incl += u;
        }
        segS[threadIdx.x] = incl - v;
        cur[threadIdx.x]  = incl - v;
    }
    __syncthreads();

    // ---- scatter (src, k) into node-sorted LDS order ----
    for (int k = threadIdx.x; k < staged; k += FTHREADS) {
        unsigned m = meta[start + k];
        int dl = m >> 26;
        int pos = atomicAdd(&cur[dl], 1);
        if (P16) {
            srtPk[pos] = ((unsigned)k << 16) | (m & 0xFFFFu);
        } else {
            srtPk[pos] = m & SRCMASK;
            srtK[pos] = (unsigned short)k;
        }
    }
    __syncthreads();

    const int c   = threadIdx.x & 31;     // channel / lane in half-wave
    const int sub = threadIdx.x >> 5;     // subgroup 0..15
    const int i_idx  = (c >> 1) & 7;
    const int pc_off = ((c >> 4) << 1) | (c & 1);
    const float* pcf = (const float*)(pcmpS + start);
    const int node0 = blockIdx.x << BSH;

#pragma unroll
    for (int r = 0; r < NPS; ++r) {
        const int gl = sub * NPS + r;
        const int n  = node0 + gl;
        const int s0 = segS[gl];
        const int e0 = s0 + cnt[gl];

        // ---- 4x straight-line unrolled register accumulation ----
        float q = 0.f;
        int j = s0;
        for (; j + 4 <= e0; j += 4) {
            unsigned p0, p1, p2, p3;
            unsigned k0, k1, k2, k3, s0v, s1v, s2v, s3v;
            if (P16) {
                p0 = srtPk[j];     p1 = srtPk[j + 1];
                p2 = srtPk[j + 2]; p3 = srtPk[j + 3];
                s0v = p0 & 0xFFFFu; k0 = p0 >> 16;
                s1v = p1 & 0xFFFFu; k1 = p1 >> 16;
                s2v = p2 & 0xFFFFu; k2 = p2 >> 16;
                s3v = p3 & 0xFFFFu; k3 = p3 >> 16;
            } else {
                s0v = srtPk[j];     k0 = srtK[j];
                s1v = srtPk[j + 1]; k1 = srtK[j + 1];
                s2v = srtPk[j + 2]; k2 = srtK[j + 2];
                s3v = srtPk[j + 3]; k3 = srtK[j + 3];
            }
            float x0 = x[(size_t)s0v * CIN + i_idx];
            float x1 = x[(size_t)s1v * CIN + i_idx];
            float x2 = x[(size_t)s2v * CIN + i_idx];
            float x3 = x[(size_t)s3v * CIN + i_idx];
            float c0 = pcf[(size_t)k0 * 4 + pc_off];
            float c1 = pcf[(size_t)k1 * 4 + pc_off];
            float c2 = pcf[(size_t)k2 * 4 + pc_off];
            float c3 = pcf[(size_t)k3 * 4 + pc_off];
            q += x0 * c0;
            q += x1 * c1;
            q += x2 * c2;
            q += x3 * c3;
        }
        for (; j < e0; ++j) {
            unsigned sv, kv;
            if (P16) {
                unsigned p = srtPk[j];
                sv = p & 0xFFFFu; kv = p >> 16;
            } else {
                sv = srtPk[j]; kv = srtK[j];
            }
            q += x[(size_t)sv * CIN + i_idx] * pcf[(size_t)kv * 4 + pc_off];
        }
        // overflow fallback (bucket > STAGE_MAX; never for this data)
        for (int t = staged; t < total; ++t) {
            unsigned m = meta[start + t];
            if ((int)(m >> 26) == gl)
                q += x[(size_t)(m & SRCMASK) * CIN + i_idx] * pcf[(size_t)t * 4 + pc_off];
        }

        // ---- epilogue straight from registers (half-wave shuffles) ----
        float a0 = 0.f, a1 = 0.f;
#pragma unroll
        for (int ri = 0; ri < NR * CIN; ++ri) {
            float w = sWrad[ri][c];
            a0 += w * __shfl(q, 2 * ri,     32);
            a1 += w * __shfl(q, 2 * ri + 1, 32);
        }
        float cs = sPh[c][0], sn = sPh[c][1];
        float re = a0 * cs - a1 * sn;
        float im = a0 * sn + a1 * cs;
        float mag = sqrtf(re * re + im * im + EPSF);
        float sc  = fmaxf(mag + sBias[0][c], 0.f) / mag;
        re *= sc; im *= sc;
#pragma unroll
        for (int L = 0; L < 3; ++L) {
            float b0 = 0.f, b1v = 0.f;
#pragma unroll
            for (int i = 0; i < COUT; ++i) {
                float w = sW[L][i][c];
                b0  += w * __shfl(re, i, 32);
                b1v += w * __shfl(im, i, 32);
            }
            float m2 = sqrtf(b0 * b0 + b1v * b1v + EPSF);
            float s2 = fmaxf(m2 + sBias[L + 1][c], 0.f) / m2;
            re = b0 * s2; im = b1v * s2;
        }
        if (n < N) {
            float2 v; v.x = re; v.y = im;
            *reinterpret_cast<float2*>(out + ((size_t)n * COUT + c) * 2) = v;
        }
    }
}

// ---------------- fallback fused kernel (meta-only, LDS atomics) ------------
__global__ __launch_bounds__(256) void fused_bucket_fallback(
    const float* __restrict__ x, const int* __restrict__ eidx,
    const float* __restrict__ pcmp, const int* __restrict__ bucketBase,
    const unsigned* __restrict__ sorted,
    const float* __restrict__ W_rad, const float* __restrict__ phase,
    const float* __restrict__ b_nl,
    const float* __restrict__ W1, const float* __restrict__ b1,
    const float* __restrict__ W2, const float* __restrict__ b2,
    const float* __restrict__ W3, const float* __restrict__ b3,
    float* __restrict__ out, int N)
{
    __shared__ float Q[BNODES][COUT];
    __shared__ float sWrad[NR * CIN][COUT];
    __shared__ float sW[3][COUT][COUT];
    __shared__ float sPh[COUT][2];
    __shared__ float sBias[4][COUT];

    for (int i = threadIdx.x; i < BNODES * COUT; i += 256) ((float*)Q)[i] = 0.f;
    for (int i = threadIdx.x; i < NR * CIN * COUT; i += 256) ((float*)sWrad)[i] = W_rad[i];
    for (int i = threadIdx.x; i < COUT * COUT; i += 256) {
        ((float*)sW[0])[i] = W1[i];
        ((float*)sW[1])[i] = W2[i];
        ((float*)sW[2])[i] = W3[i];
    }
    if (threadIdx.x < COUT) {
        float sn, cs; __sincosf(phase[threadIdx.x], &sn, &cs);
        sPh[threadIdx.x][0] = cs; sPh[threadIdx.x][1] = sn;
        sBias[0][threadIdx.x] = b_nl[threadIdx.x];
        sBias[1][threadIdx.x] = b1[threadIdx.x];
        sBias[2][threadIdx.x] = b2[threadIdx.x];
        sBias[3][threadIdx.x] = b3[threadIdx.x];
    }
    __syncthreads();

    const int c   = threadIdx.x & 31;
    const int sub = threadIdx.x >> 5;
    const int i_idx  = (c >> 1) & 7;
    const int pc_off = ((c >> 4) << 1) | (c & 1);
    const int start = bucketBase[blockIdx.x];
    const int end   = bucketBase[blockIdx.x + 1];

    for (int p = start + sub; p < end; p += 8) {
        unsigned v0 = sorted[p];
        int id0 = v0 & IDMASK;
        int s0 = eidx[id0];
        atomicAdd(&Q[v0 >> IDBITS][c],
                  x[(size_t)s0 * CIN + i_idx] * pcmp[(size_t)id0 * 4 + pc_off]);
    }
    __syncthreads();

    const int node0 = blockIdx.x << BSH;
#pragma unroll
    for (int r = 0; r < 8; ++r) {
        const int gl = r * 8 + sub;
        const int n  = node0 + gl;
        float a0 = 0.f, a1 = 0.f;
#pragma unroll
        for (int ri = 0; ri < NR * CIN; ++ri) {
            float w = sWrad[ri][c];
            a0 += w * Q[gl][2 * ri];
            a1 += w * Q[gl][2 * ri + 1];
        }
        float cs = sPh[c][0], sn = sPh[c][1];
        float re = a0 * cs - a1 * sn;
        float im = a0 * sn + a1 * cs;
        float mag = sqrtf(re * re + im * im + EPSF);
        float sc  = fmaxf(mag + sBias[0][c], 0.f) / mag;
        re *= sc; im *= sc;
#pragma unroll
        for (int L = 0; L < 3; ++L) {
            float b0 = 0.f, b1v = 0.f;
#pragma unroll
            for (int i = 0; i < COUT; ++i) {
                float w = sW[L][i][c];
                b0  += w * __shfl(re, i, 32);
                b1v += w * __shfl(im, i, 32);
            }
            float m2 = sqrtf(b0 * b0 + b1v * b1v + EPSF);
            float s2 = fmaxf(m2 + sBias[L + 1][c], 0.f) / m2;
            re = b0 * s2; im = b1v * s2;
        }
        if (n < N) {
            float2 v; v.x = re; v.y = im;
            *reinterpret_cast<float2*>(out + ((size_t)n * COUT + c) * 2) = v;
        }
    }
}

extern "C" void kernel_launch(void* const* d_in, const int* in_sizes, int n_in,
                              void* d_out, int out_size, void* d_ws, size_t ws_size,
                              hipStream_t stream)
{
    const float* x     = (const float*)d_in[0];
    const int*   eidx  = (const int*)  d_in[1];
    const float* pcmp  = (const float*)d_in[2];
    const float* W_rad = (const float*)d_in[3];
    const float* phase = (const float*)d_in[4];
    const float* b_nl  = (const float*)d_in[5];
    const float* W1    = (const float*)d_in[6];
    const float* b1    = (const float*)d_in[7];
    const float* W2    = (const float*)d_in[8];
    const float* b2    = (const float*)d_in[9];
    const float* W3    = (const float*)d_in[10];
    const float* b3    = (const float*)d_in[11];
    float* out = (float*)d_out;

    const int N = in_sizes[0] / CIN;
    const int E = in_sizes[1] / 2;
    const int nb = (N + BNODES - 1) >> BSH;
    const int nchunk = (E + CHUNK - 1) / CHUNK;

    // PACKED layout: pcmpS[E] (16B) | meta[E] (4B) | bucketCnt | bucketBase | gCursor
    float4*   pcmpS      = (float4*)d_ws;
    unsigned* meta       = (unsigned*)(pcmpS + E);
    int*      bucketCnt  = (int*)(meta + E);
    int*      bucketBase = bucketCnt + NBMAX;
    int*      gCursor    = bucketBase + NBMAX + 1;
    size_t needed = (size_t)((char*)(gCursor + NBMAX) - (char*)d_ws);

    if (ws_size >= needed) {
        hipMemsetAsync(bucketCnt, 0, (size_t)nb * sizeof(int), stream);
        bucket_hist<<<256, 256, 0, stream>>>(eidx, bucketCnt, E, nb);
        scan_init<<<1, 1024, 0, stream>>>(bucketCnt, bucketBase, gCursor, nb);
        binify<true><<<nchunk, 256, 0, stream>>>(eidx, gCursor, meta, pcmpS, pcmp, E, nb);
        if (N <= 65536) {
            fused_sorted_kernel<true><<<nb, FTHREADS, 0, stream>>>(
                x, pcmpS, meta, bucketBase,
                W_rad, phase, b_nl, W1, b1, W2, b2, W3, b3, out, N);
        } else {
            fused_sorted_kernel<false><<<nb, FTHREADS, 0, stream>>>(
                x, pcmpS, meta, bucketBase,
                W_rad, phase, b_nl, W1, b1, W2, b2, W3, b3, out, N);
        }
    } else {
        int*      bc = (int*)d_ws;
        int*      bb = bc + NBMAX;
        int*      gc = bb + NBMAX + 1;
        unsigned* so = (unsigned*)(gc + NBMAX);
        hipMemsetAsync(bc, 0, (size_t)nb * sizeof(int), stream);
        bucket_hist<<<256, 256, 0, stream>>>(eidx, bc, E, nb);
        scan_init<<<1, 1024, 0, stream>>>(bc, bb, gc, nb);
        binify<false><<<nchunk, 256, 0, stream>>>(eidx, gc, so, nullptr, pcmp, E, nb);
        fused_bucket_fallback<<<nb, 256, 0, stream>>>(
            x, eidx, pcmp, bb, so,
            W_rad, phase, b_nl, W1, b1, W2, b2, W3, b3, out, N);
    }
}

// Round 10
// 199.298 us; speedup vs baseline: 1.5502x; 1.0390x over previous
//
#include <hip/hip_runtime.h>

#define CIN 8
#define COUT 32
#define NR 2
#define EPSF 1e-6f

#define BSH 5                   // log2 nodes per bucket
#define BNODES 32               // nodes per bucket
#define NBMAX 2048              // supports N <= 65536
#define CHUNK 8192              // edges per binify block
#define IDBITS 21               // supports E < 2^21
#define IDMASK ((1u << IDBITS) - 1u)
#define SRCMASK 0x03FFFFFFu     // low 26 bits of meta = src node
#define STAGE_MAX 2048          // per-bucket staging capacity (avg 1024)

// ---------------- pass 1: coarse bucket histogram ----------------
__global__ __launch_bounds__(256) void bucket_hist(
    const int* __restrict__ eidx, int* __restrict__ bucketCnt, int E, int nb)
{
    __shared__ int cnt[NBMAX];
    for (int i = threadIdx.x; i < nb; i += 256) cnt[i] = 0;
    __syncthreads();
    for (int e = blockIdx.x * 256 + threadIdx.x; e < E; e += gridDim.x * 256)
        atomicAdd(&cnt[eidx[E + e] >> BSH], 1);
    __syncthreads();
    for (int i = threadIdx.x; i < nb; i += 256)
        if (cnt[i]) atomicAdd(&bucketCnt[i], cnt[i]);
}

// ---------------- pass 2: single-block scan -> bucket bases ----------------
__global__ __launch_bounds__(1024) void scan_init(
    const int* __restrict__ bucketCnt, int* __restrict__ bucketBase,
    int* __restrict__ gCursor, int nb)
{
    __shared__ int sA[NBMAX], sB[NBMAX];
    for (int i = threadIdx.x; i < NBMAX; i += 1024)
        sA[i] = (i < nb) ? bucketCnt[i] : 0;
    __syncthreads();
    int* src = sA; int* dst = sB;
    for (int off = 1; off < NBMAX; off <<= 1) {
        for (int i = threadIdx.x; i < NBMAX; i += 1024)
            dst[i] = src[i] + (i >= off ? src[i - off] : 0);
        __syncthreads();
        int* tmp = src; src = dst; dst = tmp;
    }
    for (int i = threadIdx.x; i < nb; i += 1024) {
        int incl = src[i];
        int base = incl - bucketCnt[i];
        bucketBase[i] = base;
        gCursor[i] = base;
        if (i == nb - 1) bucketBase[nb] = incl;
    }
}

// ------- pass 3: bin edges by bucket; PACKED also reorders pcmp+src --------
template<bool PACKED>
__global__ __launch_bounds__(256) void binify(
    const int* __restrict__ eidx, int* __restrict__ gCursor,
    unsigned* __restrict__ outMeta,     // PACKED: (dl<<26)|src ; else (dl<<21)|e
    float4*   __restrict__ pcmpS,       // PACKED only: reordered pcmp
    const float* __restrict__ pcmp, int E, int nb)
{
    __shared__ int cnt[NBMAX];
    __shared__ int sA[NBMAX], sB[NBMAX];
    __shared__ int gbase[NBMAX];
    __shared__ unsigned sid[CHUNK];

    const int e0 = blockIdx.x * CHUNK;
    const int num = min(CHUNK, E - e0);

    for (int i = threadIdx.x; i < nb; i += 256) cnt[i] = 0;
    __syncthreads();
    for (int k = threadIdx.x; k < num; k += 256)
        atomicAdd(&cnt[eidx[E + e0 + k] >> BSH], 1);
    __syncthreads();

    for (int j = threadIdx.x; j < NBMAX; j += 256) sA[j] = (j < nb) ? cnt[j] : 0;
    __syncthreads();
    int* src = sA; int* dstp = sB;
    for (int off = 1; off < NBMAX; off <<= 1) {
        for (int j = threadIdx.x; j < NBMAX; j += 256)
            dstp[j] = src[j] + (j >= off ? src[j - off] : 0);
        __syncthreads();
        int* tmp = src; src = dstp; dstp = tmp;
    }

    for (int b = threadIdx.x; b < nb; b += 256)
        gbase[b] = atomicAdd(&gCursor[b], cnt[b]);
    __syncthreads();
    for (int i = threadIdx.x; i < nb; i += 256) cnt[i] = 0;   // reuse as cursor
    __syncthreads();

    for (int k = threadIdx.x; k < num; k += 256) {
        int e = e0 + k;
        int d = eidx[E + e];
        int b = d >> BSH;
        int slot = (b ? src[b - 1] : 0) + atomicAdd(&cnt[b], 1);
        sid[slot] = ((unsigned)(d & (BNODES - 1)) << IDBITS) | (unsigned)e;
    }
    __syncthreads();

    // coalesced segment write-out
    for (int s = threadIdx.x; s < num; s += 256) {
        int lo = 0, hi = nb;
        while (lo < hi) { int mid = (lo + hi) >> 1; if (src[mid] > s) hi = mid; else lo = mid + 1; }
        int b = lo;
        int intra = s - (b ? src[b - 1] : 0);
        unsigned v = sid[s];
        int pos = gbase[b] + intra;
        if (PACKED) {
            int id = v & IDMASK;
            unsigned dl = v >> IDBITS;
            unsigned sv = (unsigned)eidx[id];
            outMeta[pos] = (dl << 26) | sv;
            pcmpS[pos] = *reinterpret_cast<const float4*>(pcmp + (size_t)id * 4);
        } else {
            outMeta[pos] = v;
        }
    }
}

// ---- pass 4: per-bucket LDS counting-sort + 4x-unrolled reg accumulation ---
// 256 threads: 8 subgroups x 4 serial nodes (BNODES=32). P16: (k<<16)|src.
template<bool P16>
__global__ __launch_bounds__(256) void fused_sorted_kernel(
    const float* __restrict__ x,          // [N, CIN]
    const float4* __restrict__ pcmpS,     // reordered pcmp, bucket-segmented
    const unsigned* __restrict__ meta,    // (dl<<26)|src per slot
    const int* __restrict__ bucketBase,   // [nb+1]
    const float* __restrict__ W_rad, const float* __restrict__ phase,
    const float* __restrict__ b_nl,
    const float* __restrict__ W1, const float* __restrict__ b1,
    const float* __restrict__ W2, const float* __restrict__ b2,
    const float* __restrict__ W3, const float* __restrict__ b3,
    float* __restrict__ out, int N)
{
    __shared__ float sWrad[NR * CIN][COUT];          // 2 KB
    __shared__ float sW[3][COUT][COUT];              // 12 KB
    __shared__ float sPh[COUT][2];
    __shared__ float sBias[4][COUT];
    __shared__ unsigned srtPk[STAGE_MAX];            // 8 KB
    __shared__ unsigned short srtK[P16 ? 2 : STAGE_MAX];
    __shared__ int cnt[BNODES], segS[BNODES], cur[BNODES];

    for (int i = threadIdx.x; i < NR * CIN * COUT; i += 256) ((float*)sWrad)[i] = W_rad[i];
    for (int i = threadIdx.x; i < COUT * COUT; i += 256) {
        ((float*)sW[0])[i] = W1[i];
        ((float*)sW[1])[i] = W2[i];
        ((float*)sW[2])[i] = W3[i];
    }
    if (threadIdx.x < COUT) {
        float sn, cs; __sincosf(phase[threadIdx.x], &sn, &cs);
        sPh[threadIdx.x][0] = cs; sPh[threadIdx.x][1] = sn;
        sBias[0][threadIdx.x] = b_nl[threadIdx.x];
        sBias[1][threadIdx.x] = b1[threadIdx.x];
        sBias[2][threadIdx.x] = b2[threadIdx.x];
        sBias[3][threadIdx.x] = b3[threadIdx.x];
    }
    if (threadIdx.x < BNODES) cnt[threadIdx.x] = 0;
    __syncthreads();

    const int start  = bucketBase[blockIdx.x];
    const int total  = bucketBase[blockIdx.x + 1] - start;
    const int staged = min(total, STAGE_MAX);

    // ---- histogram by local node ----
    for (int k = threadIdx.x; k < staged; k += 256)
        atomicAdd(&cnt[meta[start + k] >> 26], 1);
    __syncthreads();

    // ---- exclusive scan over 32 counters (first half-wave) ----
    if (threadIdx.x < BNODES) {
        int v = cnt[threadIdx.x];
        int incl = v;
#pragma unroll
        for (int off = 1; off < BNODES; off <<= 1) {
            int u = __shfl_up(incl, off, BNODES);
            if (threadIdx.x >= off) incl += u;
        }
        segS[threadIdx.x] = incl - v;
        cur[threadIdx.x]  = incl - v;
    }
    __syncthreads();

    // ---- scatter (src, k) into node-sorted LDS order ----
    for (int k = threadIdx.x; k < staged; k += 256) {
        unsigned m = meta[start + k];
        int dl = m >> 26;
        int pos = atomicAdd(&cur[dl], 1);
        if (P16) {
            srtPk[pos] = ((unsigned)k << 16) | (m & 0xFFFFu);
        } else {
            srtPk[pos] = m & SRCMASK;
            srtK[pos] = (unsigned short)k;
        }
    }
    __syncthreads();

    const int c   = threadIdx.x & 31;     // channel / lane in half-wave
    const int sub = threadIdx.x >> 5;     // subgroup 0..7
    const int i_idx  = (c >> 1) & 7;
    const int pc_off = ((c >> 4) << 1) | (c & 1);
    const float* pcf = (const float*)(pcmpS + start);   // SGPR base
    const int node0 = blockIdx.x << BSH;

#pragma unroll
    for (int r = 0; r < 4; ++r) {
        const int gl = sub * 4 + r;
        const int n  = node0 + gl;
        const int s0 = segS[gl];
        const int e0 = s0 + cnt[gl];

        // ---- 4x straight-line unrolled, int32-indexed accumulation ----
        float q = 0.f;
        int j = s0;
        for (; j + 4 <= e0; j += 4) {
            int k0, k1, k2, k3, s0v, s1v, s2v, s3v;
            if (P16) {
                unsigned p0 = srtPk[j],     p1 = srtPk[j + 1];
                unsigned p2 = srtPk[j + 2], p3 = srtPk[j + 3];
                s0v = (int)(p0 & 0xFFFFu); k0 = (int)(p0 >> 16);
                s1v = (int)(p1 & 0xFFFFu); k1 = (int)(p1 >> 16);
                s2v = (int)(p2 & 0xFFFFu); k2 = (int)(p2 >> 16);
                s3v = (int)(p3 & 0xFFFFu); k3 = (int)(p3 >> 16);
            } else {
                s0v = (int)srtPk[j];     k0 = srtK[j];
                s1v = (int)srtPk[j + 1]; k1 = srtK[j + 1];
                s2v = (int)srtPk[j + 2]; k2 = srtK[j + 2];
                s3v = (int)srtPk[j + 3]; k3 = srtK[j + 3];
            }
            float x0 = x[(s0v << 3) + i_idx];
            float x1 = x[(s1v << 3) + i_idx];
            float x2 = x[(s2v << 3) + i_idx];
            float x3 = x[(s3v << 3) + i_idx];
            float c0 = pcf[(k0 << 2) | pc_off];
            float c1 = pcf[(k1 << 2) | pc_off];
            float c2 = pcf[(k2 << 2) | pc_off];
            float c3 = pcf[(k3 << 2) | pc_off];
            q += x0 * c0;
            q += x1 * c1;
            q += x2 * c2;
            q += x3 * c3;
        }
        for (; j < e0; ++j) {
            int sv, kv;
            if (P16) {
                unsigned p = srtPk[j];
                sv = (int)(p & 0xFFFFu); kv = (int)(p >> 16);
            } else {
                sv = (int)srtPk[j]; kv = srtK[j];
            }
            q += x[(sv << 3) + i_idx] * pcf[(kv << 2) | pc_off];
        }
        // overflow fallback (bucket > STAGE_MAX; never for this data)
        for (int t = staged; t < total; ++t) {
            unsigned m = meta[start + t];
            if ((int)(m >> 26) == gl)
                q += x[(int)(m & SRCMASK) * CIN + i_idx] * pcf[(t << 2) | pc_off];
        }

        // ---- epilogue straight from registers (half-wave shuffles) ----
        float a0 = 0.f, a1 = 0.f;
#pragma unroll
        for (int ri = 0; ri < NR * CIN; ++ri) {
            float w = sWrad[ri][c];
            a0 += w * __shfl(q, 2 * ri,     32);
            a1 += w * __shfl(q, 2 * ri + 1, 32);
        }
        float cs = sPh[c][0], sn = sPh[c][1];
        float re = a0 * cs - a1 * sn;
        float im = a0 * sn + a1 * cs;
        float mag = sqrtf(re * re + im * im + EPSF);
        float sc  = fmaxf(mag + sBias[0][c], 0.f) / mag;
        re *= sc; im *= sc;
#pragma unroll
        for (int L = 0; L < 3; ++L) {
            float b0 = 0.f, b1v = 0.f;
#pragma unroll
            for (int i = 0; i < COUT; ++i) {
                float w = sW[L][i][c];
                b0  += w * __shfl(re, i, 32);
                b1v += w * __shfl(im, i, 32);
            }
            float m2 = sqrtf(b0 * b0 + b1v * b1v + EPSF);
            float s2 = fmaxf(m2 + sBias[L + 1][c], 0.f) / m2;
            re = b0 * s2; im = b1v * s2;
        }
        if (n < N) {
            float2 v; v.x = re; v.y = im;
            *reinterpret_cast<float2*>(out + ((n << 6) + (c << 1))) = v;
        }
    }
}

// ---------------- fallback fused kernel (meta-only, LDS atomics) ------------
__global__ __launch_bounds__(256) void fused_bucket_fallback(
    const float* __restrict__ x, const int* __restrict__ eidx,
    const float* __restrict__ pcmp, const int* __restrict__ bucketBase,
    const unsigned* __restrict__ sorted,
    const float* __restrict__ W_rad, const float* __restrict__ phase,
    const float* __restrict__ b_nl,
    const float* __restrict__ W1, const float* __restrict__ b1,
    const float* __restrict__ W2, const float* __restrict__ b2,
    const float* __restrict__ W3, const float* __restrict__ b3,
    float* __restrict__ out, int N)
{
    __shared__ float Q[BNODES][COUT];
    __shared__ float sWrad[NR * CIN][COUT];
    __shared__ float sW[3][COUT][COUT];
    __shared__ float sPh[COUT][2];
    __shared__ float sBias[4][COUT];

    for (int i = threadIdx.x; i < BNODES * COUT; i += 256) ((float*)Q)[i] = 0.f;
    for (int i = threadIdx.x; i < NR * CIN * COUT; i += 256) ((float*)sWrad)[i] = W_rad[i];
    for (int i = threadIdx.x; i < COUT * COUT; i += 256) {
        ((float*)sW[0])[i] = W1[i];
        ((float*)sW[1])[i] = W2[i];
        ((float*)sW[2])[i] = W3[i];
    }
    if (threadIdx.x < COUT) {
        float sn, cs; __sincosf(phase[threadIdx.x], &sn, &cs);
        sPh[threadIdx.x][0] = cs; sPh[threadIdx.x][1] = sn;
        sBias[0][threadIdx.x] = b_nl[threadIdx.x];
        sBias[1][threadIdx.x] = b1[threadIdx.x];
        sBias[2][threadIdx.x] = b2[threadIdx.x];
        sBias[3][threadIdx.x] = b3[threadIdx.x];
    }
    __syncthreads();

    const int c   = threadIdx.x & 31;
    const int sub = threadIdx.x >> 5;
    const int i_idx  = (c >> 1) & 7;
    const int pc_off = ((c >> 4) << 1) | (c & 1);
    const int start = bucketBase[blockIdx.x];
    const int end   = bucketBase[blockIdx.x + 1];

    for (int p = start + sub; p < end; p += 8) {
        unsigned v0 = sorted[p];
        int id0 = v0 & IDMASK;
        int s0 = eidx[id0];
        atomicAdd(&Q[v0 >> IDBITS][c],
                  x[(size_t)s0 * CIN + i_idx] * pcmp[(size_t)id0 * 4 + pc_off]);
    }
    __syncthreads();

    const int node0 = blockIdx.x << BSH;
#pragma unroll
    for (int r = 0; r < 4; ++r) {
        const int gl = r * 8 + sub;
        const int n  = node0 + gl;
        float a0 = 0.f, a1 = 0.f;
#pragma unroll
        for (int ri = 0; ri < NR * CIN; ++ri) {
            float w = sWrad[ri][c];
            a0 += w * Q[gl][2 * ri];
            a1 += w * Q[gl][2 * ri + 1];
        }
        float cs = sPh[c][0], sn = sPh[c][1];
        float re = a0 * cs - a1 * sn;
        float im = a0 * sn + a1 * cs;
        float mag = sqrtf(re * re + im * im + EPSF);
        float sc  = fmaxf(mag + sBias[0][c], 0.f) / mag;
        re *= sc; im *= sc;
#pragma unroll
        for (int L = 0; L < 3; ++L) {
            float b0 = 0.f, b1v = 0.f;
#pragma unroll
            for (int i = 0; i < COUT; ++i) {
                float w = sW[L][i][c];
                b0  += w * __shfl(re, i, 32);
                b1v += w * __shfl(im, i, 32);
            }
            float m2 = sqrtf(b0 * b0 + b1v * b1v + EPSF);
            float s2 = fmaxf(m2 + sBias[L + 1][c], 0.f) / m2;
            re = b0 * s2; im = b1v * s2;
        }
        if (n < N) {
            float2 v; v.x = re; v.y = im;
            *reinterpret_cast<float2*>(out + ((size_t)n * COUT + c) * 2) = v;
        }
    }
}

extern "C" void kernel_launch(void* const* d_in, const int* in_sizes, int n_in,
                              void* d_out, int out_size, void* d_ws, size_t ws_size,
                              hipStream_t stream)
{
    const float* x     = (const float*)d_in[0];
    const int*   eidx  = (const int*)  d_in[1];
    const float* pcmp  = (const float*)d_in[2];
    const float* W_rad = (const float*)d_in[3];
    const float* phase = (const float*)d_in[4];
    const float* b_nl  = (const float*)d_in[5];
    const float* W1    = (const float*)d_in[6];
    const float* b1    = (const float*)d_in[7];
    const float* W2    = (const float*)d_in[8];
    const float* b2    = (const float*)d_in[9];
    const float* W3    = (const float*)d_in[10];
    const float* b3    = (const float*)d_in[11];
    float* out = (float*)d_out;

    const int N = in_sizes[0] / CIN;
    const int E = in_sizes[1] / 2;
    const int nb = (N + BNODES - 1) >> BSH;
    const int nchunk = (E + CHUNK - 1) / CHUNK;

    // PACKED layout: pcmpS[E] (16B) | meta[E] (4B) | bucketCnt | bucketBase | gCursor
    float4*   pcmpS      = (float4*)d_ws;
    unsigned* meta       = (unsigned*)(pcmpS + E);
    int*      bucketCnt  = (int*)(meta + E);
    int*      bucketBase = bucketCnt + NBMAX;
    int*      gCursor    = bucketBase + NBMAX + 1;
    size_t needed = (size_t)((char*)(gCursor + NBMAX) - (char*)d_ws);

    if (ws_size >= needed) {
        hipMemsetAsync(bucketCnt, 0, (size_t)nb * sizeof(int), stream);
        bucket_hist<<<256, 256, 0, stream>>>(eidx, bucketCnt, E, nb);
        scan_init<<<1, 1024, 0, stream>>>(bucketCnt, bucketBase, gCursor, nb);
        binify<true><<<nchunk, 256, 0, stream>>>(eidx, gCursor, meta, pcmpS, pcmp, E, nb);
        if (N <= 65536) {
            fused_sorted_kernel<true><<<nb, 256, 0, stream>>>(
                x, pcmpS, meta, bucketBase,
                W_rad, phase, b_nl, W1, b1, W2, b2, W3, b3, out, N);
        } else {
            fused_sorted_kernel<false><<<nb, 256, 0, stream>>>(
                x, pcmpS, meta, bucketBase,
                W_rad, phase, b_nl, W1, b1, W2, b2, W3, b3, out, N);
        }
    } else {
        int*      bc = (int*)d_ws;
        int*      bb = bc + NBMAX;
        int*      gc = bb + NBMAX + 1;
        unsigned* so = (unsigned*)(gc + NBMAX);
        hipMemsetAsync(bc, 0, (size_t)nb * sizeof(int), stream);
        bucket_hist<<<256, 256, 0, stream>>>(eidx, bc, E, nb);
        scan_init<<<1, 1024, 0, stream>>>(bc, bb, gc, nb);
        binify<false><<<nchunk, 256, 0, stream>>>(eidx, gc, so, nullptr, pcmp, E, nb);
        fused_bucket_fallback<<<nb, 256, 0, stream>>>(
            x, eidx, pcmp, bb, so,
            W_rad, phase, b_nl, W1, b1, W2, b2, W3, b3, out, N);
    }
}